// Round 9
// baseline (964.994 us; speedup 1.0000x reference)
//
#include <hip/hip_runtime.h>

typedef unsigned short u16;
typedef __attribute__((ext_vector_type(8))) short short8v;
typedef __attribute__((ext_vector_type(4))) float f32x4;

#define PSTR 304L              // padded time stride
#define OFF_SAUX 9109504L
#define OFF_S    9502720L
#define CHSTR (32L*256L*PSTR)  // A elems per channel-group g

static __device__ __forceinline__ float bf2f(u16 u) {
  return __uint_as_float(((unsigned int)u) << 16);
}
static __device__ __forceinline__ u16 f2bf(float f) {
  unsigned int i = __float_as_uint(f);
  i += 0x7FFFu + ((i >> 16) & 1u);          // RNE
  return (u16)(i >> 16);
}

// ---------------------------------------------------------------- adj softmax
static __device__ void adj_body(int row, const float* __restrict__ emb,
                                u16* __restrict__ adjb) {
  const int m = threadIdx.x;
  __shared__ float sred[8];
  float er[16];
#pragma unroll
  for (int e = 0; e < 16; ++e) er[e] = emb[row * 16 + e];
  float d = 0.f;
#pragma unroll
  for (int e = 0; e < 16; ++e) d += er[e] * emb[m * 16 + e];
  if (m == row) d -= 10.f;
  float v = d;
#pragma unroll
  for (int off = 32; off; off >>= 1) v = fmaxf(v, __shfl_xor(v, off, 64));
  const int wid = m >> 6, lane = m & 63;
  if (lane == 0) sred[wid] = v;
  __syncthreads();
  const float mx = fmaxf(fmaxf(sred[0], sred[1]), fmaxf(sred[2], sred[3]));
  const float p = expf(d - mx);
  v = p;
#pragma unroll
  for (int off = 32; off; off >>= 1) v += __shfl_xor(v, off, 64);
  if (lane == 0) sred[4 + wid] = v;
  __syncthreads();
  const float sum = sred[4] + sred[5] + sred[6] + sred[7];
  adjb[row * 256 + m] = f2bf(p / sum);
}

// ------------------------------------------------- pack conv weights -> bf16
static __device__ void prepw_body(int bid, const float* __restrict__ c1w,
                                  const float* __restrict__ c2w,
                                  u16* __restrict__ wB) {
  const int idx = bid * 256 + threadIdx.x;   // < 156*2048 exactly
  const int kk = idx >> 11;            // g*12+k
  const int rem = idx & 2047;
  const int j = rem >> 5, chp = rem & 31;
  const int pslot = chp >> 3, chlo = chp & 7;
  const int sl = pslot ^ ((j >> 1) & 3);   // logical slot stored here
  const int ch = sl * 8 + chlo;
  const int g = kk / 12, k = kk - g * 12;
  const int cin = g * 32 + ch;
  const float* src = (j < 32) ? c1w : c2w;
  const int jj = j & 31;
  wB[idx] = f2bf(src[(jj * 416 + cin) * 12 + k]);
}

// ------------------------------------------------------- fused norm pipeline
static __device__ __forceinline__ void wscan2(float& s1, float& s2, int lane) {
#pragma unroll
  for (int off = 1; off < 64; off <<= 1) {
    float a = __shfl_up(s1, off, 64);
    float b = __shfl_up(s2, off, 64);
    if (lane >= off) { s1 += a; s2 += b; }
  }
}

static __device__ void norm_body(int bid, const float* __restrict__ x,
                                 u16* __restrict__ xcat) {
  const int wid = threadIdx.x >> 6, lane = threadIdx.x & 63;
  const long row = (long)bid * 4 + wid;
  const int b = (int)(row >> 13);
  const int c = (int)((row >> 8) & 31);
  const int n = (int)(row & 255);
  const float* xr = x + row * 288;
  __shared__ float bufA[4][304], bufB[4][304], cs1[4][312], cs2[4][312], sst[4][80];
  float* bA = bufA[wid];
  float* bB = bufB[wid];
  float* p1 = cs1[wid];
  float* p2 = cs2[wid];
  float* psm = sst[wid];
  float* psi = sst[wid] + 24;
  float* psd = sst[wid] + 48;
  const long chb = (long)b * 416 * 256 + n;

  for (int j = 0; j < 5; ++j) { int t = j * 64 + lane; if (t < 288) bA[t] = xr[t]; }

  auto scanbuf = [&](float* src) {
    float ca = 0.f, cb = 0.f;
    if (lane == 0) { p1[0] = 0.f; p2[0] = 0.f; }
    for (int j = 0; j < 5; ++j) {
      int t = j * 64 + lane;
      float v = (t < 288) ? src[t] : 0.f;
      float s1 = v, s2 = v * v;
      wscan2(s1, s2, lane);
      if (t < 288) { p1[t + 1] = ca + s1; p2[t + 1] = cb + s2; }
      ca += __shfl(s1, 63, 64);
      cb += __shfl(s2, 63, 64);
    }
  };

  // ---- long term_norm, L=48
  scanbuf(bA);
  for (int j = 0; j < 5; ++j) {
    int t = j * 64 + lane; if (t >= 288) continue;
    float S, Q;
    if (t >= 47) { S = p1[t + 1] - p1[t - 47]; Q = p2[t + 1] - p2[t - 47]; }
    else         { S = p1[48];                 Q = p2[48]; }
    float m = S * (1.f / 48.f);
    float var = Q * (1.f / 48.f) - m * m + 1e-5f;
    float sd = sqrtf(var);
    float iv = rsqrtf(var + 1.f);
    float xv = bA[t];
    float x1 = (xv - m) * iv;
    bB[t] = x1;
    xcat[(chb + (long)(c)      * 256) * PSTR + 1 + t] = f2bf(xv);
    xcat[(chb + (long)(32 + c) * 256) * PSTR + 1 + t] = f2bf(x1);
    xcat[(chb + (long)(64 + c) * 256) * PSTR + 1 + t] = f2bf(m);
    xcat[(chb + (long)(96 + c) * 256) * PSTR + 1 + t] = f2bf(sd);
  }
  {
    float S = p1[288] - p1[240], Q = p2[288] - p2[240];
    float m = S * (1.f / 48.f);
    float var = Q * (1.f / 48.f) - m * m + 1e-5f;
    float sd = sqrtf(var);
    if (lane < 12) {
      xcat[(chb + (long)(c)      * 256) * PSTR + 289 + lane] = f2bf(bA[287]);
      xcat[(chb + (long)(64 + c) * 256) * PSTR + 289 + lane] = f2bf(m);
      xcat[(chb + (long)(96 + c) * 256) * PSTR + 289 + lane] = f2bf(sd);
    }
    if (lane == 0) {
      xcat[(chb + (long)(c)      * 256) * PSTR] = 0;
      xcat[(chb + (long)(32 + c) * 256) * PSTR] = 0;
      xcat[(chb + (long)(64 + c) * 256) * PSTR] = 0;
      xcat[(chb + (long)(96 + c) * 256) * PSTR] = 0;
    }
  }
  // ---- seasonal_norm, P=24 (on bB = x1)
  if (lane < 24) {
    float S = 0.f, Q = 0.f;
#pragma unroll
    for (int i2 = 0; i2 < 12; ++i2) { float v = bB[lane + 24 * i2]; S += v; Q += v * v; }
    float m = S * (1.f / 12.f);
    float var = Q * (1.f / 12.f) - m * m + 1e-5f;
    psm[lane] = m; psi[lane] = rsqrtf(var + 1.f); psd[lane] = sqrtf(var);
  }
  for (int j = 0; j < 5; ++j) {
    int t = j * 64 + lane; if (t >= 288) continue;
    int ph = t % 24;
    float m = psm[ph];
    float x2v = (bB[t] - m) * psi[ph];
    bA[t] = x2v;
    xcat[(chb + (long)(128 + c) * 256) * PSTR + 1 + t] = f2bf(x2v);
    xcat[(chb + (long)(160 + c) * 256) * PSTR + 1 + t] = f2bf(m);
    xcat[(chb + (long)(192 + c) * 256) * PSTR + 1 + t] = f2bf(psd[ph]);
  }
  if (lane < 12) {
    xcat[(chb + (long)(160 + c) * 256) * PSTR + 289 + lane] = f2bf(psm[lane]);
    xcat[(chb + (long)(192 + c) * 256) * PSTR + 289 + lane] = f2bf(psd[lane]);
  }
  if (lane == 0) {
    xcat[(chb + (long)(128 + c) * 256) * PSTR] = 0;
    xcat[(chb + (long)(160 + c) * 256) * PSTR] = 0;
    xcat[(chb + (long)(192 + c) * 256) * PSTR] = 0;
  }
  // ---- short term_norm, L=12 (on bA = x2)
  scanbuf(bA);
  for (int j = 0; j < 5; ++j) {
    int t = j * 64 + lane; if (t >= 288) continue;
    float S, Q;
    if (t >= 11) { S = p1[t + 1] - p1[t - 11]; Q = p2[t + 1] - p2[t - 11]; }
    else         { S = p1[12];                 Q = p2[12]; }
    float m = S * (1.f / 12.f);
    float var = Q * (1.f / 12.f) - m * m + 1e-5f;
    float sd = sqrtf(var);
    float iv = rsqrtf(var + 1.f);
    float x3v = (bA[t] - m) * iv;
    xcat[(chb + (long)(224 + c) * 256) * PSTR + 1 + t] = f2bf(x3v);
    xcat[(chb + (long)(256 + c) * 256) * PSTR + 1 + t] = f2bf(m);
    xcat[(chb + (long)(288 + c) * 256) * PSTR + 1 + t] = f2bf(sd);
  }
  {
    float S = p1[288] - p1[276], Q = p2[288] - p2[276];
    float m = S * (1.f / 12.f);
    float var = Q * (1.f / 12.f) - m * m + 1e-5f;
    float sd = sqrtf(var);
    if (lane < 12) {
      xcat[(chb + (long)(256 + c) * 256) * PSTR + 289 + lane] = f2bf(m);
      xcat[(chb + (long)(288 + c) * 256) * PSTR + 289 + lane] = f2bf(sd);
    }
    if (lane == 0) {
      xcat[(chb + (long)(224 + c) * 256) * PSTR] = 0;
      xcat[(chb + (long)(256 + c) * 256) * PSTR] = 0;
      xcat[(chb + (long)(288 + c) * 256) * PSTR] = 0;
    }
  }
}

// ---------------- front: norm (0..8191) | adj (8192..8447) | prepw (8448..9695)
__global__ __launch_bounds__(256) void k_front(const float* __restrict__ x,
    const float* __restrict__ emb, const float* __restrict__ c1w,
    const float* __restrict__ c2w, u16* __restrict__ xcat,
    u16* __restrict__ adjb, u16* __restrict__ wB) {
  const int bid = blockIdx.x;
  if (bid < 8192)       norm_body(bid, x, xcat);
  else if (bid < 8448)  adj_body(bid - 8192, emb, adjb);
  else                  prepw_body(bid - 8448, c1w, c2w, wB);
}

// --------------------------------------------- residual extrapolation (tiny)
static __device__ void re_body(long gid, u16* __restrict__ xcat,
                               const float* __restrict__ W,
                               const float* __restrict__ bias, int srcch) {
  const int o = (int)(gid % 384);
  const long bn = gid / 384;
  const int n = (int)(bn & 255);
  const int b = (int)(bn >> 8);
  const float* wr = W + o * 160;
  float acc = bias[o];
  for (int c = 0; c < 32; ++c) {
    const long rb = ((long)(b * 416 + srcch + c) * 256 + n) * PSTR + 284;
#pragma unroll
    for (int k = 0; k < 5; ++k) acc += wr[c * 5 + k] * bf2f(xcat[rb + k]);
  }
  const int cd = o & 31, p = o >> 5;
  xcat[((long)(b * 416 + srcch + cd) * 256 + n) * PSTR + 289 + p] = f2bf(acc);
}

__global__ __launch_bounds__(256) void k_re4(u16* __restrict__ xcat,
                                             const float* __restrict__ W,
                                             const float* __restrict__ bias) {
  re_body((long)blockIdx.x * 256 + threadIdx.x, xcat, W, bias, 320);
}

// ----------------------------------------------------- spatial norm (MFMA)
static __device__ void spatial_body(int sid, u16* __restrict__ xcat,
                                    const u16* __restrict__ adjb) {
  const int gx = sid % 20;       // 0..19
  const int slice = sid / 20;    // 0..127
  const int tcn = gx >> 2, ncb = gx & 3;
  const int b = slice >> 5, c = slice & 31;
  const int t0 = tcn * 64, n0 = ncb * 64;
  const int tid = threadIdx.x;
  const int wid = tid >> 6, lane = tid & 63;
  const int wm = wid >> 1, wn = wid & 1;
  const int l15 = lane & 15, lq = lane >> 4;
  __shared__ __align__(16) u16 BT[2][64 * 40];
  __shared__ __align__(16) u16 BT2[2][64 * 40];
  const f32x4 vz = {0.f, 0.f, 0.f, 0.f};
  f32x4 aM[2][2], aV[2][2];
#pragma unroll
  for (int i = 0; i < 2; ++i)
#pragma unroll
    for (int j = 0; j < 2; ++j) { aM[i][j] = vz; aV[i][j] = vz; }
  const long base7 = (long)(b * 416 + 224 + c) * 256;
  u16 rv[8];
#pragma unroll
  for (int r = 0; r < 8; ++r) {
    int idx = tid + r * 256; int ml = idx >> 6, s = idx & 63;
    rv[r] = xcat[(base7 + ml) * PSTR + 1 + t0 + s];
  }
#pragma unroll
  for (int r = 0; r < 8; ++r) {
    int idx = tid + r * 256; int ml = idx >> 6, s = idx & 63;
    float v = bf2f(rv[r]);
    BT[0][s * 40 + ml] = rv[r];
    BT2[0][s * 40 + ml] = f2bf(v * v);
  }
  __syncthreads();
  int cur = 0;
  for (int kk = 0; kk < 8; ++kk) {
    u16 rn[8];
    if (kk < 7) {
#pragma unroll
      for (int r = 0; r < 8; ++r) {
        int idx = tid + r * 256; int ml = idx >> 6, s = idx & 63;
        rn[r] = xcat[(base7 + (long)((kk + 1) * 32 + ml)) * PSTR + 1 + t0 + s];
      }
    }
    const short8v a0 = *(const short8v*)(adjb + (long)(n0 + wm * 32 + l15) * 256 + kk * 32 + lq * 8);
    const short8v a1 = *(const short8v*)(adjb + (long)(n0 + wm * 32 + 16 + l15) * 256 + kk * 32 + lq * 8);
    const u16* bt = BT[cur];
    const u16* bq = BT2[cur];
    const short8v b0 = *(const short8v*)(bt + (wn * 32 + l15) * 40 + lq * 8);
    const short8v b1 = *(const short8v*)(bt + (wn * 32 + 16 + l15) * 40 + lq * 8);
    const short8v q0 = *(const short8v*)(bq + (wn * 32 + l15) * 40 + lq * 8);
    const short8v q1 = *(const short8v*)(bq + (wn * 32 + 16 + l15) * 40 + lq * 8);
    aM[0][0] = __builtin_amdgcn_mfma_f32_16x16x32_bf16(a0, b0, aM[0][0], 0, 0, 0);
    aM[0][1] = __builtin_amdgcn_mfma_f32_16x16x32_bf16(a0, b1, aM[0][1], 0, 0, 0);
    aM[1][0] = __builtin_amdgcn_mfma_f32_16x16x32_bf16(a1, b0, aM[1][0], 0, 0, 0);
    aM[1][1] = __builtin_amdgcn_mfma_f32_16x16x32_bf16(a1, b1, aM[1][1], 0, 0, 0);
    aV[0][0] = __builtin_amdgcn_mfma_f32_16x16x32_bf16(a0, q0, aV[0][0], 0, 0, 0);
    aV[0][1] = __builtin_amdgcn_mfma_f32_16x16x32_bf16(a0, q1, aV[0][1], 0, 0, 0);
    aV[1][0] = __builtin_amdgcn_mfma_f32_16x16x32_bf16(a1, q0, aV[1][0], 0, 0, 0);
    aV[1][1] = __builtin_amdgcn_mfma_f32_16x16x32_bf16(a1, q1, aV[1][1], 0, 0, 0);
    __syncthreads();
    if (kk < 7) {
#pragma unroll
      for (int r = 0; r < 8; ++r) {
        int idx = tid + r * 256; int ml = idx >> 6, s = idx & 63;
        float v = bf2f(rn[r]);
        BT[cur ^ 1][s * 40 + ml] = rn[r];
        BT2[cur ^ 1][s * 40 + ml] = f2bf(v * v);
      }
    }
    __syncthreads();
    cur ^= 1;
  }
#pragma unroll
  for (int mf = 0; mf < 2; ++mf)
#pragma unroll
    for (int nf = 0; nf < 2; ++nf)
#pragma unroll
      for (int e = 0; e < 4; ++e) {
        const int i = wm * 32 + mf * 16 + lq * 4 + e;
        const int j = wn * 32 + nf * 16 + l15;
        const int nn = n0 + i, tt2 = t0 + j;
        if (tt2 < 288) {
          const float mean = aM[mf][nf][e], ex2 = aV[mf][nf][e];
          const float var = ex2 - mean * mean + 1e-5f;
          const float sd = sqrtf(var);
          const float iv = rsqrtf(var + 1.f);
          const float x3c = bf2f(xcat[(base7 + nn) * PSTR + 1 + tt2]);
          const float x4 = (x3c - mean) * iv;
          const long r10 = ((long)(b * 416 + 320 + c) * 256 + nn) * PSTR;
          const long r11 = ((long)(b * 416 + 352 + c) * 256 + nn) * PSTR;
          const long r12 = ((long)(b * 416 + 384 + c) * 256 + nn) * PSTR;
          xcat[r10 + 1 + tt2] = f2bf(x4);
          xcat[r11 + 1 + tt2] = f2bf(mean);
          xcat[r12 + 1 + tt2] = f2bf(sd);
          if (tt2 == 287) {
            for (int p = 0; p < 12; ++p) {
              xcat[r11 + 289 + p] = f2bf(mean);
              xcat[r12 + 289 + p] = f2bf(sd);
            }
          }
          if (tt2 == 0) { xcat[r10] = 0; xcat[r11] = 0; xcat[r12] = 0; }
        }
      }
}

// ---------------- mid: spatial (0..2559) | re1/re2/re3 (2560..7167)
__global__ __launch_bounds__(256) void k_mid(u16* __restrict__ xcat,
    const u16* __restrict__ adjb,
    const float* __restrict__ w1, const float* __restrict__ b1,
    const float* __restrict__ w2, const float* __restrict__ b2,
    const float* __restrict__ w3, const float* __restrict__ b3) {
  const int bid = blockIdx.x;
  if (bid < 2560) { spatial_body(bid, xcat, adjb); return; }
  const int sub = bid - 2560;             // 0..4607
  const int which = sub / 1536;
  const long gid = (long)(sub - which * 1536) * 256 + threadIdx.x;
  if (which == 0)      re_body(gid, xcat, w1, b1, 32);
  else if (which == 1) re_body(gid, xcat, w2, b2, 128);
  else                 re_body(gid, xcat, w3, b3, 224);
}

// --------------------------------------------------- main time-conv (g1,g2)
// Barrier-free K-loop: A per-wave LDS [t][40] XOR-swizzled (same-wave
// write->read, in-order DS pipe); B read straight from global (L2-hot wB,
// convA-proven pattern). One __syncthreads before the epilogue only.
template<int MT>
static __device__ void convG_body(int t0, int by,
    const u16* __restrict__ xcat, const u16* __restrict__ wB,
    const float* __restrict__ c1b, const float* __restrict__ c2b,
    const float* __restrict__ rsw, const float* __restrict__ rsb,
    const float* __restrict__ skw, const float* __restrict__ skb,
    float* __restrict__ out, unsigned char* smem) {
  const int b = by >> 6;
  const int tid = threadIdx.x;
  const int wid = tid >> 6, lane = tid & 63;
  const int n_abs = (by & 63) * 4 + wid;
  const int l15 = lane & 15, lq = lane >> 4;
  constexpr int NCH = (MT == 2) ? 9 : 5;     // staging chunks per lane
  constexpr int TKS = (MT == 2) ? 18 : 10;   // 8-t chunks per channel

  u16* Asm = (u16*)smem;                 // 4 waves x 5760 u16 = 46080 B

  int sch[NCH], stk[NCH];
  const u16* baseR[NCH];
#pragma unroll
  for (int r = 0; r < NCH; ++r) {
    int cc = r * 64 + lane;
    int s = cc / TKS, tk = cc - s * TKS;
    sch[r] = s; stk[r] = tk;
    baseR[r] = xcat + ((long)(b * 416 + s) * 256 + n_abs) * PSTR + t0 + tk * 8;
  }
  u16* aw = Asm + wid * 5760;

#define AWRITE() { \
    _Pragma("unroll") \
    for (int r = 0; r < NCH; ++r) { \
      u16 pc[8]; *(uint4*)pc = aR[r]; \
      const int pcol = ((((sch[r] >> 3) ^ stk[r]) & 3) << 3) + (sch[r] & 7); \
      _Pragma("unroll") \
      for (int e = 0; e < 8; ++e) aw[(stk[r] * 8 + e) * 40 + pcol] = pc[e]; \
    } }

  // ---- prologue: A(g=0) into LDS (same-wave, no barrier needed)
  uint4 aR[NCH];
#pragma unroll
  for (int r = 0; r < NCH; ++r) aR[r] = *(const uint4*)baseR[r];
  AWRITE();

  const f32x4 vz = {0.f, 0.f, 0.f, 0.f};
  f32x4 acc[4 * MT][4];
#pragma unroll
  for (int i = 0; i < 4 * MT; ++i)
#pragma unroll
    for (int j = 0; j < 4; ++j) acc[i][j] = vz;

  const int bsw = (lq ^ ((l15 >> 1) & 3)) << 3;

  for (int g = 0; g < 13; ++g) {
    const u16* wg = wB + (long)g * 12 * 2048 + bsw;
#pragma unroll
    for (int K = 0; K < 12; ++K) {
      const u16* wk = wg + K * 2048;
      short8v bf[4];
#pragma unroll
      for (int f = 0; f < 4; ++f)
        bf[f] = *(const short8v*)(wk + (f * 16 + l15) * 32);
      short8v af[4 * MT];
#pragma unroll
      for (int f = 0; f < 4 * MT; ++f) {
        const int tt = K + f * 16 + l15;
        af[f] = *(const short8v*)(aw + tt * 40 + (((lq ^ (tt >> 3)) & 3) << 3));
      }
#pragma unroll
      for (int i = 0; i < 4 * MT; ++i)
#pragma unroll
        for (int j = 0; j < 4; ++j)
          acc[i][j] = __builtin_amdgcn_mfma_f32_16x16x32_bf16(af[i], bf[j], acc[i][j], 0, 0, 0);
    }
    if (g < 12) {  // load + rewrite A for g+1 (per-wave private, program order)
#pragma unroll
      for (int r = 0; r < NCH; ++r) aR[r] = *(const uint4*)(baseR[r] + (long)(g + 1) * CHSTR);
      AWRITE();
    }
  }
#undef AWRITE
  __syncthreads();   // pw regions below overlap other waves' A regions

  // ---- epilogue: MT passes of 64 rows; per-wave pad-33 LDS, fused 1x1
#pragma unroll
  for (int pass = 0; pass < MT; ++pass) {
    float* pw = (float*)smem + wid * 2112;   // 64 rows x 33 f32 per wave
#pragma unroll
    for (int fi = 0; fi < 4; ++fi)
#pragma unroll
      for (int nf = 0; nf < 2; ++nf)
#pragma unroll
        for (int e = 0; e < 4; ++e) {
          const int trow = fi * 16 + lq * 4 + e;
          const int cch = nf * 16 + l15;
          const float g1 = acc[pass * 4 + fi][nf][e] + c1b[cch];
          const float g2 = acc[pass * 4 + fi][nf + 2][e] + c2b[cch];
          pw[trow * 33 + cch] = g1 * g2;
        }
    float pv[32];
    {
      const float* prow = pw + lane * 33;
#pragma unroll
      for (int c = 0; c < 32; ++c) pv[c] = prow[c];
    }
    const int t = t0 + pass * 64 + lane;
    if (t0 + pass * 64 + 63 < 278) {  // uniform residual-only path
      for (int o = 0; o < 32; ++o) {
        float s = rsb[o];
        const float* wr = rsw + o * 32;
#pragma unroll
        for (int c = 0; c < 32; ++c) s += wr[c] * pv[c];
        out[((long)(b * 32 + o) * 256 + n_abs) * 278 + t] = s;
      }
    } else {              // mixed res / skip / discard
      const bool isres = t < 278;
      const bool isskip = (t >= 278) && (t < 290);
      for (int o = 0; o < 32; ++o) {
        const float* wr = (isres ? rsw : skw) + o * 32;
        float s = (isres ? rsb : skb)[o];
#pragma unroll
        for (int c = 0; c < 32; ++c) s += wr[c] * pv[c];
        if (isres)       out[((long)(b * 32 + o) * 256 + n_abs) * 278 + t] = s;
        else if (isskip) out[OFF_S + ((long)(b * 32 + o) * 256 + n_abs) * 12 + (t - 278)] = s;
      }
    }
  }
}

// Grid (3,256): x=0,1 -> 128-wide tiles; x=2 -> 64-wide tail at t0=256.
__global__ __launch_bounds__(256, 2) void k_convG(
    const u16* __restrict__ xcat, const u16* __restrict__ wB,
    const float* __restrict__ c1b, const float* __restrict__ c2b,
    const float* __restrict__ rsw, const float* __restrict__ rsb,
    const float* __restrict__ skw, const float* __restrict__ skb,
    float* __restrict__ out) {
  __shared__ __align__(16) unsigned char smem[46080];
  if (blockIdx.x < 2)
    convG_body<2>(blockIdx.x * 128, blockIdx.y, xcat, wB, c1b, c2b, rsw, rsb, skw, skb, out, smem);
  else
    convG_body<1>(256, blockIdx.y, xcat, wB, c1b, c2b, rsw, rsb, skw, skb, out, smem);
}

// ------------------------------------------- aux conv (a1,a2) tail -> s_aux
// Grid 1024: block = one (b,n); 4 waves split the 8 g-groups 2-each; LDS
// partial sums reduced across waves; vectorized uint4 staging from t=272.
__global__ __launch_bounds__(256) void k_convA(const u16* __restrict__ xcat,
    const u16* __restrict__ wB, const float* __restrict__ c1b,
    const float* __restrict__ c2b, const float* __restrict__ skw,
    const float* __restrict__ skb, float* __restrict__ out) {
  const int tid = threadIdx.x;
  const int wid = tid >> 6, lane = tid & 63;
  const int row = blockIdx.x;            // (b,n)
  const int b = row >> 8, n = row & 255;
  const int l15 = lane & 15, lq = lane >> 4;
  __shared__ __align__(16) u16 ATa[4][2][36 * 40];  // per wave, 2 g-tiles
  __shared__ float apL[4][16 * 68];
  const int gtab[8] = {2, 3, 5, 6, 8, 9, 11, 12};
  const long bnbase = (long)b * 416 * 256 + n;

  // stage: per wave, its 2 g-tiles; tile rows t' = t-272 in [0,32)
#pragma unroll
  for (int tau = 0; tau < 2; ++tau) {
    const int g = gtab[wid * 2 + tau];
    u16* at = ATa[wid][tau];
#pragma unroll
    for (int h = 0; h < 2; ++h) {
      const int c = lane + h * 64;       // 0..127
      const int ch = c >> 2, part = c & 3;
      const uint4 v = *(const uint4*)(xcat +
          (bnbase + (long)(g * 32 + ch) * 256) * PSTR + 272 + part * 8);
      u16 pc[8]; *(uint4*)pc = v;
#pragma unroll
      for (int e = 0; e < 8; ++e) at[(part * 8 + e) * 40 + ch] = pc[e];
    }
  }

  const f32x4 vz = {0.f, 0.f, 0.f, 0.f};
  f32x4 acc[4] = {vz, vz, vz, vz};
  const int bsw = (lq ^ ((l15 >> 1) & 3)) << 3;
#pragma unroll
  for (int tau = 0; tau < 2; ++tau) {
    const int g = gtab[wid * 2 + tau];
    const u16* at = ATa[wid][tau];
    for (int k = 0; k < 12; ++k) {
      const short8v af = *(const short8v*)(at + (l15 + k + 6) * 40 + lq * 8);
#pragma unroll
      for (int nf = 0; nf < 4; ++nf) {
        const short8v bf = *(const short8v*)(wB + (long)(g * 12 + k) * 2048 + (nf * 16 + l15) * 32 + bsw);
        acc[nf] = __builtin_amdgcn_mfma_f32_16x16x32_bf16(af, bf, acc[nf], 0, 0, 0);
      }
    }
  }
  float* ap = apL[wid];
#pragma unroll
  for (int nf = 0; nf < 4; ++nf)
#pragma unroll
    for (int e = 0; e < 4; ++e)
      ap[(lq * 4 + e) * 68 + nf * 16 + l15] = acc[nf][e];
  __syncthreads();
  // reduce 4 wave-partials into apL[0]
  for (int idx = tid; idx < 1024; idx += 256) {
    const int m = idx >> 6, j = idx & 63;
    apL[0][m * 68 + j] = apL[0][m * 68 + j] + apL[1][m * 68 + j]
                       + apL[2][m * 68 + j] + apL[3][m * 68 + j];
  }
  __syncthreads();
  for (int task = tid; task < 384; task += 256) {
    const int o = task & 31, tt = task >> 5;   // tt 0..11
    float s = skb[o];
#pragma unroll
    for (int c2 = 0; c2 < 32; ++c2)
      s += skw[o * 32 + c2] * (apL[0][tt * 68 + c2] + c1b[c2])
                            * (apL[0][tt * 68 + 32 + c2] + c2b[c2]);
    out[OFF_SAUX + ((long)(b * 32 + o) * 256 + n) * 12 + tt] = s;
  }
}

// ---------------------------------------------------------------- launcher
extern "C" void kernel_launch(void* const* d_in, const int* in_sizes, int n_in,
                              void* d_out, int out_size, void* d_ws, size_t ws_size,
                              hipStream_t stream) {
  const float* x   = (const float*)d_in[0];
  const float* emb = (const float*)d_in[1];
  const float* c1w = (const float*)d_in[2];
  const float* c1b = (const float*)d_in[3];
  const float* c2w = (const float*)d_in[4];
  const float* c2b = (const float*)d_in[5];
  const float* skw = (const float*)d_in[6];
  const float* skb = (const float*)d_in[7];
  const float* rsw = (const float*)d_in[8];
  const float* rsb = (const float*)d_in[9];
  float* out = (float*)d_out;

  u16* xcat = (u16*)d_ws;                                   // 4*416*256*304 elems
  u16* wB   = xcat + (4L * 416 * 256 * 304 + 2048);         // 156*2048
  u16* adjb = wB + 156L * 2048;                             // 256*256

  k_front<<<dim3(9696), dim3(256), 0, stream>>>(x, emb, c1w, c2w, xcat, adjb, wB);
  k_mid<<<dim3(7168), dim3(256), 0, stream>>>(xcat, adjb,
      (const float*)d_in[10], (const float*)d_in[11],
      (const float*)d_in[12], (const float*)d_in[13],
      (const float*)d_in[14], (const float*)d_in[15]);
  k_re4<<<dim3(1536), dim3(256), 0, stream>>>(xcat, (const float*)d_in[16], (const float*)d_in[17]);
  k_convG<<<dim3(3, 256), dim3(256), 0, stream>>>(xcat, wB, c1b, c2b, rsw, rsb, skw, skb, out);
  k_convA<<<dim3(1024), dim3(256), 0, stream>>>(xcat, wB, c1b, c2b, skw, skb, out);
}

// Round 10
// 940.260 us; speedup vs baseline: 1.0263x; 1.0263x over previous
//
#include <hip/hip_runtime.h>

typedef unsigned short u16;
typedef __attribute__((ext_vector_type(8))) short short8v;
typedef __attribute__((ext_vector_type(4))) float f32x4;

#define PSTR 304L              // padded time stride
#define OFF_SAUX 9109504L
#define OFF_S    9502720L
#define CHSTR (32L*256L*PSTR)  // A elems per channel-group g

static __device__ __forceinline__ float bf2f(u16 u) {
  return __uint_as_float(((unsigned int)u) << 16);
}
static __device__ __forceinline__ u16 f2bf(float f) {
  unsigned int i = __float_as_uint(f);
  i += 0x7FFFu + ((i >> 16) & 1u);          // RNE
  return (u16)(i >> 16);
}

static __device__ __forceinline__ void gload16(const void* g, void* l) {
  __builtin_amdgcn_global_load_lds(
      (const __attribute__((address_space(1))) unsigned int*)g,
      (__attribute__((address_space(3))) unsigned int*)l, 16, 0, 0);
}

// ---------------------------------------------------------------- adj softmax
static __device__ void adj_body(int row, const float* __restrict__ emb,
                                u16* __restrict__ adjb) {
  const int m = threadIdx.x;
  __shared__ float sred[8];
  float er[16];
#pragma unroll
  for (int e = 0; e < 16; ++e) er[e] = emb[row * 16 + e];
  float d = 0.f;
#pragma unroll
  for (int e = 0; e < 16; ++e) d += er[e] * emb[m * 16 + e];
  if (m == row) d -= 10.f;
  float v = d;
#pragma unroll
  for (int off = 32; off; off >>= 1) v = fmaxf(v, __shfl_xor(v, off, 64));
  const int wid = m >> 6, lane = m & 63;
  if (lane == 0) sred[wid] = v;
  __syncthreads();
  const float mx = fmaxf(fmaxf(sred[0], sred[1]), fmaxf(sred[2], sred[3]));
  const float p = expf(d - mx);
  v = p;
#pragma unroll
  for (int off = 32; off; off >>= 1) v += __shfl_xor(v, off, 64);
  if (lane == 0) sred[4 + wid] = v;
  __syncthreads();
  const float sum = sred[4] + sred[5] + sred[6] + sred[7];
  adjb[row * 256 + m] = f2bf(p / sum);
}

// ------------------------------------------------- pack conv weights -> bf16
static __device__ void prepw_body(int bid, const float* __restrict__ c1w,
                                  const float* __restrict__ c2w,
                                  u16* __restrict__ wB) {
  const int idx = bid * 256 + threadIdx.x;   // < 156*2048 exactly
  const int kk = idx >> 11;            // g*12+k
  const int rem = idx & 2047;
  const int j = rem >> 5, chp = rem & 31;
  const int pslot = chp >> 3, chlo = chp & 7;
  const int sl = pslot ^ ((j >> 1) & 3);   // logical slot stored here
  const int ch = sl * 8 + chlo;
  const int g = kk / 12, k = kk - g * 12;
  const int cin = g * 32 + ch;
  const float* src = (j < 32) ? c1w : c2w;
  const int jj = j & 31;
  wB[idx] = f2bf(src[(jj * 416 + cin) * 12 + k]);
}

// ------------------------------------------------------- fused norm pipeline
static __device__ __forceinline__ void wscan2(float& s1, float& s2, int lane) {
#pragma unroll
  for (int off = 1; off < 64; off <<= 1) {
    float a = __shfl_up(s1, off, 64);
    float b = __shfl_up(s2, off, 64);
    if (lane >= off) { s1 += a; s2 += b; }
  }
}

static __device__ void norm_body(int bid, const float* __restrict__ x,
                                 u16* __restrict__ xcat) {
  const int wid = threadIdx.x >> 6, lane = threadIdx.x & 63;
  const long row = (long)bid * 4 + wid;
  const int b = (int)(row >> 13);
  const int c = (int)((row >> 8) & 31);
  const int n = (int)(row & 255);
  const float* xr = x + row * 288;
  __shared__ float bufA[4][304], bufB[4][304], cs1[4][312], cs2[4][312], sst[4][80];
  float* bA = bufA[wid];
  float* bB = bufB[wid];
  float* p1 = cs1[wid];
  float* p2 = cs2[wid];
  float* psm = sst[wid];
  float* psi = sst[wid] + 24;
  float* psd = sst[wid] + 48;
  const long chb = (long)b * 416 * 256 + n;

  for (int j = 0; j < 5; ++j) { int t = j * 64 + lane; if (t < 288) bA[t] = xr[t]; }

  auto scanbuf = [&](float* src) {
    float ca = 0.f, cb = 0.f;
    if (lane == 0) { p1[0] = 0.f; p2[0] = 0.f; }
    for (int j = 0; j < 5; ++j) {
      int t = j * 64 + lane;
      float v = (t < 288) ? src[t] : 0.f;
      float s1 = v, s2 = v * v;
      wscan2(s1, s2, lane);
      if (t < 288) { p1[t + 1] = ca + s1; p2[t + 1] = cb + s2; }
      ca += __shfl(s1, 63, 64);
      cb += __shfl(s2, 63, 64);
    }
  };

  // ---- long term_norm, L=48
  scanbuf(bA);
  for (int j = 0; j < 5; ++j) {
    int t = j * 64 + lane; if (t >= 288) continue;
    float S, Q;
    if (t >= 47) { S = p1[t + 1] - p1[t - 47]; Q = p2[t + 1] - p2[t - 47]; }
    else         { S = p1[48];                 Q = p2[48]; }
    float m = S * (1.f / 48.f);
    float var = Q * (1.f / 48.f) - m * m + 1e-5f;
    float sd = sqrtf(var);
    float iv = rsqrtf(var + 1.f);
    float xv = bA[t];
    float x1 = (xv - m) * iv;
    bB[t] = x1;
    xcat[(chb + (long)(c)      * 256) * PSTR + 1 + t] = f2bf(xv);
    xcat[(chb + (long)(32 + c) * 256) * PSTR + 1 + t] = f2bf(x1);
    xcat[(chb + (long)(64 + c) * 256) * PSTR + 1 + t] = f2bf(m);
    xcat[(chb + (long)(96 + c) * 256) * PSTR + 1 + t] = f2bf(sd);
  }
  {
    float S = p1[288] - p1[240], Q = p2[288] - p2[240];
    float m = S * (1.f / 48.f);
    float var = Q * (1.f / 48.f) - m * m + 1e-5f;
    float sd = sqrtf(var);
    if (lane < 12) {
      xcat[(chb + (long)(c)      * 256) * PSTR + 289 + lane] = f2bf(bA[287]);
      xcat[(chb + (long)(64 + c) * 256) * PSTR + 289 + lane] = f2bf(m);
      xcat[(chb + (long)(96 + c) * 256) * PSTR + 289 + lane] = f2bf(sd);
    }
    if (lane == 0) {
      xcat[(chb + (long)(c)      * 256) * PSTR] = 0;
      xcat[(chb + (long)(32 + c) * 256) * PSTR] = 0;
      xcat[(chb + (long)(64 + c) * 256) * PSTR] = 0;
      xcat[(chb + (long)(96 + c) * 256) * PSTR] = 0;
    }
  }
  // ---- seasonal_norm, P=24 (on bB = x1)
  if (lane < 24) {
    float S = 0.f, Q = 0.f;
#pragma unroll
    for (int i2 = 0; i2 < 12; ++i2) { float v = bB[lane + 24 * i2]; S += v; Q += v * v; }
    float m = S * (1.f / 12.f);
    float var = Q * (1.f / 12.f) - m * m + 1e-5f;
    psm[lane] = m; psi[lane] = rsqrtf(var + 1.f); psd[lane] = sqrtf(var);
  }
  for (int j = 0; j < 5; ++j) {
    int t = j * 64 + lane; if (t >= 288) continue;
    int ph = t % 24;
    float m = psm[ph];
    float x2v = (bB[t] - m) * psi[ph];
    bA[t] = x2v;
    xcat[(chb + (long)(128 + c) * 256) * PSTR + 1 + t] = f2bf(x2v);
    xcat[(chb + (long)(160 + c) * 256) * PSTR + 1 + t] = f2bf(m);
    xcat[(chb + (long)(192 + c) * 256) * PSTR + 1 + t] = f2bf(psd[ph]);
  }
  if (lane < 12) {
    xcat[(chb + (long)(160 + c) * 256) * PSTR + 289 + lane] = f2bf(psm[lane]);
    xcat[(chb + (long)(192 + c) * 256) * PSTR + 289 + lane] = f2bf(psd[lane]);
  }
  if (lane == 0) {
    xcat[(chb + (long)(128 + c) * 256) * PSTR] = 0;
    xcat[(chb + (long)(160 + c) * 256) * PSTR] = 0;
    xcat[(chb + (long)(192 + c) * 256) * PSTR] = 0;
  }
  // ---- short term_norm, L=12 (on bA = x2)
  scanbuf(bA);
  for (int j = 0; j < 5; ++j) {
    int t = j * 64 + lane; if (t >= 288) continue;
    float S, Q;
    if (t >= 11) { S = p1[t + 1] - p1[t - 11]; Q = p2[t + 1] - p2[t - 11]; }
    else         { S = p1[12];                 Q = p2[12]; }
    float m = S * (1.f / 12.f);
    float var = Q * (1.f / 12.f) - m * m + 1e-5f;
    float sd = sqrtf(var);
    float iv = rsqrtf(var + 1.f);
    float x3v = (bA[t] - m) * iv;
    xcat[(chb + (long)(224 + c) * 256) * PSTR + 1 + t] = f2bf(x3v);
    xcat[(chb + (long)(256 + c) * 256) * PSTR + 1 + t] = f2bf(m);
    xcat[(chb + (long)(288 + c) * 256) * PSTR + 1 + t] = f2bf(sd);
  }
  {
    float S = p1[288] - p1[276], Q = p2[288] - p2[276];
    float m = S * (1.f / 12.f);
    float var = Q * (1.f / 12.f) - m * m + 1e-5f;
    float sd = sqrtf(var);
    if (lane < 12) {
      xcat[(chb + (long)(256 + c) * 256) * PSTR + 289 + lane] = f2bf(m);
      xcat[(chb + (long)(288 + c) * 256) * PSTR + 289 + lane] = f2bf(sd);
    }
    if (lane == 0) {
      xcat[(chb + (long)(224 + c) * 256) * PSTR] = 0;
      xcat[(chb + (long)(256 + c) * 256) * PSTR] = 0;
      xcat[(chb + (long)(288 + c) * 256) * PSTR] = 0;
    }
  }
}

// ---------------- front: norm (0..8191) | adj (8192..8447) | prepw (8448..9695)
__global__ __launch_bounds__(256) void k_front(const float* __restrict__ x,
    const float* __restrict__ emb, const float* __restrict__ c1w,
    const float* __restrict__ c2w, u16* __restrict__ xcat,
    u16* __restrict__ adjb, u16* __restrict__ wB) {
  const int bid = blockIdx.x;
  if (bid < 8192)       norm_body(bid, x, xcat);
  else if (bid < 8448)  adj_body(bid - 8192, emb, adjb);
  else                  prepw_body(bid - 8448, c1w, c2w, wB);
}

// --------------------------------------------- residual extrapolation (tiny)
static __device__ void re_body(long gid, u16* __restrict__ xcat,
                               const float* __restrict__ W,
                               const float* __restrict__ bias, int srcch) {
  const int o = (int)(gid % 384);
  const long bn = gid / 384;
  const int n = (int)(bn & 255);
  const int b = (int)(bn >> 8);
  const float* wr = W + o * 160;
  float acc = bias[o];
  for (int c = 0; c < 32; ++c) {
    const long rb = ((long)(b * 416 + srcch + c) * 256 + n) * PSTR + 284;
#pragma unroll
    for (int k = 0; k < 5; ++k) acc += wr[c * 5 + k] * bf2f(xcat[rb + k]);
  }
  const int cd = o & 31, p = o >> 5;
  xcat[((long)(b * 416 + srcch + cd) * 256 + n) * PSTR + 289 + p] = f2bf(acc);
}

__global__ __launch_bounds__(256) void k_re4(u16* __restrict__ xcat,
                                             const float* __restrict__ W,
                                             const float* __restrict__ bias) {
  re_body((long)blockIdx.x * 256 + threadIdx.x, xcat, W, bias, 320);
}

// ----------------------------------------------------- spatial norm (MFMA)
static __device__ void spatial_body(int sid, u16* __restrict__ xcat,
                                    const u16* __restrict__ adjb) {
  const int gx = sid % 20;       // 0..19
  const int slice = sid / 20;    // 0..127
  const int tcn = gx >> 2, ncb = gx & 3;
  const int b = slice >> 5, c = slice & 31;
  const int t0 = tcn * 64, n0 = ncb * 64;
  const int tid = threadIdx.x;
  const int wid = tid >> 6, lane = tid & 63;
  const int wm = wid >> 1, wn = wid & 1;
  const int l15 = lane & 15, lq = lane >> 4;
  __shared__ __align__(16) u16 BT[2][64 * 40];
  __shared__ __align__(16) u16 BT2[2][64 * 40];
  const f32x4 vz = {0.f, 0.f, 0.f, 0.f};
  f32x4 aM[2][2], aV[2][2];
#pragma unroll
  for (int i = 0; i < 2; ++i)
#pragma unroll
    for (int j = 0; j < 2; ++j) { aM[i][j] = vz; aV[i][j] = vz; }
  const long base7 = (long)(b * 416 + 224 + c) * 256;
  u16 rv[8];
#pragma unroll
  for (int r = 0; r < 8; ++r) {
    int idx = tid + r * 256; int ml = idx >> 6, s = idx & 63;
    rv[r] = xcat[(base7 + ml) * PSTR + 1 + t0 + s];
  }
#pragma unroll
  for (int r = 0; r < 8; ++r) {
    int idx = tid + r * 256; int ml = idx >> 6, s = idx & 63;
    float v = bf2f(rv[r]);
    BT[0][s * 40 + ml] = rv[r];
    BT2[0][s * 40 + ml] = f2bf(v * v);
  }
  __syncthreads();
  int cur = 0;
  for (int kk = 0; kk < 8; ++kk) {
    u16 rn[8];
    if (kk < 7) {
#pragma unroll
      for (int r = 0; r < 8; ++r) {
        int idx = tid + r * 256; int ml = idx >> 6, s = idx & 63;
        rn[r] = xcat[(base7 + (long)((kk + 1) * 32 + ml)) * PSTR + 1 + t0 + s];
      }
    }
    const short8v a0 = *(const short8v*)(adjb + (long)(n0 + wm * 32 + l15) * 256 + kk * 32 + lq * 8);
    const short8v a1 = *(const short8v*)(adjb + (long)(n0 + wm * 32 + 16 + l15) * 256 + kk * 32 + lq * 8);
    const u16* bt = BT[cur];
    const u16* bq = BT2[cur];
    const short8v b0 = *(const short8v*)(bt + (wn * 32 + l15) * 40 + lq * 8);
    const short8v b1 = *(const short8v*)(bt + (wn * 32 + 16 + l15) * 40 + lq * 8);
    const short8v q0 = *(const short8v*)(bq + (wn * 32 + l15) * 40 + lq * 8);
    const short8v q1 = *(const short8v*)(bq + (wn * 32 + 16 + l15) * 40 + lq * 8);
    aM[0][0] = __builtin_amdgcn_mfma_f32_16x16x32_bf16(a0, b0, aM[0][0], 0, 0, 0);
    aM[0][1] = __builtin_amdgcn_mfma_f32_16x16x32_bf16(a0, b1, aM[0][1], 0, 0, 0);
    aM[1][0] = __builtin_amdgcn_mfma_f32_16x16x32_bf16(a1, b0, aM[1][0], 0, 0, 0);
    aM[1][1] = __builtin_amdgcn_mfma_f32_16x16x32_bf16(a1, b1, aM[1][1], 0, 0, 0);
    aV[0][0] = __builtin_amdgcn_mfma_f32_16x16x32_bf16(a0, q0, aV[0][0], 0, 0, 0);
    aV[0][1] = __builtin_amdgcn_mfma_f32_16x16x32_bf16(a0, q1, aV[0][1], 0, 0, 0);
    aV[1][0] = __builtin_amdgcn_mfma_f32_16x16x32_bf16(a1, q0, aV[1][0], 0, 0, 0);
    aV[1][1] = __builtin_amdgcn_mfma_f32_16x16x32_bf16(a1, q1, aV[1][1], 0, 0, 0);
    __syncthreads();
    if (kk < 7) {
#pragma unroll
      for (int r = 0; r < 8; ++r) {
        int idx = tid + r * 256; int ml = idx >> 6, s = idx & 63;
        float v = bf2f(rn[r]);
        BT[cur ^ 1][s * 40 + ml] = rn[r];
        BT2[cur ^ 1][s * 40 + ml] = f2bf(v * v);
      }
    }
    __syncthreads();
    cur ^= 1;
  }
#pragma unroll
  for (int mf = 0; mf < 2; ++mf)
#pragma unroll
    for (int nf = 0; nf < 2; ++nf)
#pragma unroll
      for (int e = 0; e < 4; ++e) {
        const int i = wm * 32 + mf * 16 + lq * 4 + e;
        const int j = wn * 32 + nf * 16 + l15;
        const int nn = n0 + i, tt2 = t0 + j;
        if (tt2 < 288) {
          const float mean = aM[mf][nf][e], ex2 = aV[mf][nf][e];
          const float var = ex2 - mean * mean + 1e-5f;
          const float sd = sqrtf(var);
          const float iv = rsqrtf(var + 1.f);
          const float x3c = bf2f(xcat[(base7 + nn) * PSTR + 1 + tt2]);
          const float x4 = (x3c - mean) * iv;
          const long r10 = ((long)(b * 416 + 320 + c) * 256 + nn) * PSTR;
          const long r11 = ((long)(b * 416 + 352 + c) * 256 + nn) * PSTR;
          const long r12 = ((long)(b * 416 + 384 + c) * 256 + nn) * PSTR;
          xcat[r10 + 1 + tt2] = f2bf(x4);
          xcat[r11 + 1 + tt2] = f2bf(mean);
          xcat[r12 + 1 + tt2] = f2bf(sd);
          if (tt2 == 287) {
            for (int p = 0; p < 12; ++p) {
              xcat[r11 + 289 + p] = f2bf(mean);
              xcat[r12 + 289 + p] = f2bf(sd);
            }
          }
          if (tt2 == 0) { xcat[r10] = 0; xcat[r11] = 0; xcat[r12] = 0; }
        }
      }
}

// ---------------- mid: spatial (0..2559) | re1/re2/re3 (2560..7167)
__global__ __launch_bounds__(256) void k_mid(u16* __restrict__ xcat,
    const u16* __restrict__ adjb,
    const float* __restrict__ w1, const float* __restrict__ b1,
    const float* __restrict__ w2, const float* __restrict__ b2,
    const float* __restrict__ w3, const float* __restrict__ b3) {
  const int bid = blockIdx.x;
  if (bid < 2560) { spatial_body(bid, xcat, adjb); return; }
  const int sub = bid - 2560;             // 0..4607
  const int which = sub / 1536;
  const long gid = (long)(sub - which * 1536) * 256 + threadIdx.x;
  if (which == 0)      re_body(gid, xcat, w1, b1, 32);
  else if (which == 1) re_body(gid, xcat, w2, b2, 128);
  else                 re_body(gid, xcat, w3, b3, 224);
}

// --------------------------------------------------- main time-conv (g1,g2)
// Round-8 structure; B staged as 4-block QUADS (16KB) one quad ahead,
// double-buffered -> 39 barrier-drains instead of 78.
template<int MT>
static __device__ void convG_body(int t0, int by,
    const u16* __restrict__ xcat, const u16* __restrict__ wB,
    const float* __restrict__ c1b, const float* __restrict__ c2b,
    const float* __restrict__ rsw, const float* __restrict__ rsb,
    const float* __restrict__ skw, const float* __restrict__ skb,
    float* __restrict__ out, unsigned char* smem) {
  const int b = by >> 6;
  const int tid = threadIdx.x;
  const int wid = tid >> 6, lane = tid & 63;
  const int n_abs = (by & 63) * 4 + wid;
  const int l15 = lane & 15, lq = lane >> 4;
  constexpr int NCH = (MT == 2) ? 9 : 5;     // staging chunks per lane
  constexpr int TKS = (MT == 2) ? 18 : 10;   // 8-t chunks per channel

  u16* Asm = (u16*)smem;                 // 4 waves x 5760 u16 = 46080 B
  u16* Bsm = (u16*)(smem + 46080);       // 2 bufs x 4 blocks x 2048 u16 = 32768 B

  int sch[NCH], stk[NCH];
  const u16* baseR[NCH];
#pragma unroll
  for (int r = 0; r < NCH; ++r) {
    int cc = r * 64 + lane;
    int s = cc / TKS, tk = cc - s * TKS;
    sch[r] = s; stk[r] = tk;
    baseR[r] = xcat + ((long)(b * 416 + s) * 256 + n_abs) * PSTR + t0 + tk * 8;
  }
  u16* aw = Asm + wid * 5760;

#define AWRITE() { \
    _Pragma("unroll") \
    for (int r = 0; r < NCH; ++r) { \
      u16 pc[8]; *(uint4*)pc = aR[r]; \
      const int pcol = ((((sch[r] >> 3) ^ stk[r]) & 3) << 3) + (sch[r] & 7); \
      _Pragma("unroll") \
      for (int e = 0; e < 8; ++e) aw[(stk[r] * 8 + e) * 40 + pcol] = pc[e]; \
    } }

  // ---- prologue: A(g=0) into LDS, aR <- g=1, stage B quad 0
  uint4 aR[NCH];
#pragma unroll
  for (int r = 0; r < NCH; ++r) aR[r] = *(const uint4*)baseR[r];
  AWRITE();
#pragma unroll
  for (int r = 0; r < NCH; ++r) aR[r] = *(const uint4*)(baseR[r] + CHSTR);
#pragma unroll
  for (int j = 0; j < 4; ++j)
    gload16(wB + (long)j * 2048 + wid * 512 + lane * 8, Bsm + j * 2048 + wid * 512);
  __syncthreads();   // drains DMA: quad 0 ready; A(g0) written

  const f32x4 vz = {0.f, 0.f, 0.f, 0.f};
  f32x4 acc[4 * MT][4];
#pragma unroll
  for (int i = 0; i < 4 * MT; ++i)
#pragma unroll
    for (int j = 0; j < 4; ++j) acc[i][j] = vz;

  const u16* bwl = Bsm + l15 * 32 + ((lq ^ ((l15 >> 1) & 3)) << 3);

  int q = 0;  // quad index 0..38; quad q = blocks 4q..4q+3
  for (int g = 0; g < 13; ++g) {
    for (int qp = 0; qp < 3; ++qp) {
      if (q < 38) {  // stage next quad into the other buffer
        const long kkn = (long)(q + 1) * 4;
        const int bufn = ((q + 1) & 1) * 8192;
#pragma unroll
        for (int j = 0; j < 4; ++j)
          gload16(wB + (kkn + j) * 2048 + wid * 512 + lane * 8,
                  Bsm + bufn + j * 2048 + wid * 512);
      }
      const int bufc = (q & 1) * 8192;
#pragma unroll
      for (int kh = 0; kh < 4; ++kh) {
        const int K = qp * 4 + kh;
        short8v af[4 * MT], bf[4];
#pragma unroll
        for (int f = 0; f < 4 * MT; ++f) {
          const int tt = K + f * 16 + l15;
          af[f] = *(const short8v*)(aw + tt * 40 + (((lq ^ (tt >> 3)) & 3) << 3));
        }
#pragma unroll
        for (int f = 0; f < 4; ++f)
          bf[f] = *(const short8v*)(bwl + bufc + kh * 2048 + f * 512);
#pragma unroll
        for (int i = 0; i < 4 * MT; ++i)
#pragma unroll
          for (int j = 0; j < 4; ++j)
            acc[i][j] = __builtin_amdgcn_mfma_f32_16x16x32_bf16(af[i], bf[j], acc[i][j], 0, 0, 0);
      }
      __syncthreads();  // drains DMA(q+1); all waves done reading buf q
      ++q;
    }
    if (g < 12) {  // A rewrite for g+1 (per-wave private, program order)
      AWRITE();
      if (g < 11) {
#pragma unroll
        for (int r = 0; r < NCH; ++r) aR[r] = *(const uint4*)(baseR[r] + (long)(g + 2) * CHSTR);
      }
    }
  }
#undef AWRITE
  __syncthreads();

  // ---- epilogue: MT passes of 64 rows; per-wave pad-33 LDS, fused 1x1
#pragma unroll
  for (int pass = 0; pass < MT; ++pass) {
    float* pw = (float*)smem + wid * 2112;   // 64 rows x 33 f32 per wave
#pragma unroll
    for (int fi = 0; fi < 4; ++fi)
#pragma unroll
      for (int nf = 0; nf < 2; ++nf)
#pragma unroll
        for (int e = 0; e < 4; ++e) {
          const int trow = fi * 16 + lq * 4 + e;
          const int cch = nf * 16 + l15;
          const float g1 = acc[pass * 4 + fi][nf][e] + c1b[cch];
          const float g2 = acc[pass * 4 + fi][nf + 2][e] + c2b[cch];
          pw[trow * 33 + cch] = g1 * g2;
        }
    float pv[32];
    {
      const float* prow = pw + lane * 33;
#pragma unroll
      for (int c = 0; c < 32; ++c) pv[c] = prow[c];
    }
    const int t = t0 + pass * 64 + lane;
    if (t0 + pass * 64 + 63 < 278) {  // uniform residual-only path
      for (int o = 0; o < 32; ++o) {
        float s = rsb[o];
        const float* wr = rsw + o * 32;
#pragma unroll
        for (int c = 0; c < 32; ++c) s += wr[c] * pv[c];
        out[((long)(b * 32 + o) * 256 + n_abs) * 278 + t] = s;
      }
    } else {              // mixed res / skip / discard
      const bool isres = t < 278;
      const bool isskip = (t >= 278) && (t < 290);
      for (int o = 0; o < 32; ++o) {
        const float* wr = (isres ? rsw : skw) + o * 32;
        float s = (isres ? rsb : skb)[o];
#pragma unroll
        for (int c = 0; c < 32; ++c) s += wr[c] * pv[c];
        if (isres)       out[((long)(b * 32 + o) * 256 + n_abs) * 278 + t] = s;
        else if (isskip) out[OFF_S + ((long)(b * 32 + o) * 256 + n_abs) * 12 + (t - 278)] = s;
      }
    }
  }
}

// Grid (3,256): x=0,1 -> 128-wide tiles; x=2 -> 64-wide tail at t0=256.
__global__ __launch_bounds__(256, 2) void k_convG(
    const u16* __restrict__ xcat, const u16* __restrict__ wB,
    const float* __restrict__ c1b, const float* __restrict__ c2b,
    const float* __restrict__ rsw, const float* __restrict__ rsb,
    const float* __restrict__ skw, const float* __restrict__ skb,
    float* __restrict__ out) {
  __shared__ __align__(16) unsigned char smem[78848];
  if (blockIdx.x < 2)
    convG_body<2>(blockIdx.x * 128, blockIdx.y, xcat, wB, c1b, c2b, rsw, rsb, skw, skb, out, smem);
  else
    convG_body<1>(256, blockIdx.y, xcat, wB, c1b, c2b, rsw, rsb, skw, skb, out, smem);
}

// ------------------------------------------- aux conv (a1,a2) tail -> s_aux
// Grid 1024: block = one (b,n); 4 waves split the 8 g-groups 2-each; LDS
// partial sums reduced across waves; vectorized uint4 staging from t=272.
__global__ __launch_bounds__(256) void k_convA(const u16* __restrict__ xcat,
    const u16* __restrict__ wB, const float* __restrict__ c1b,
    const float* __restrict__ c2b, const float* __restrict__ skw,
    const float* __restrict__ skb, float* __restrict__ out) {
  const int tid = threadIdx.x;
  const int wid = tid >> 6, lane = tid & 63;
  const int row = blockIdx.x;            // (b,n)
  const int b = row >> 8, n = row & 255;
  const int l15 = lane & 15, lq = lane >> 4;
  __shared__ __align__(16) u16 ATa[4][2][36 * 40];  // per wave, 2 g-tiles
  __shared__ float apL[4][16 * 68];
  const int gtab[8] = {2, 3, 5, 6, 8, 9, 11, 12};
  const long bnbase = (long)b * 416 * 256 + n;

  // stage: per wave, its 2 g-tiles; tile rows t' = t-272 in [0,32)
#pragma unroll
  for (int tau = 0; tau < 2; ++tau) {
    const int g = gtab[wid * 2 + tau];
    u16* at = ATa[wid][tau];
#pragma unroll
    for (int h = 0; h < 2; ++h) {
      const int c = lane + h * 64;       // 0..127
      const int ch = c >> 2, part = c & 3;
      const uint4 v = *(const uint4*)(xcat +
          (bnbase + (long)(g * 32 + ch) * 256) * PSTR + 272 + part * 8);
      u16 pc[8]; *(uint4*)pc = v;
#pragma unroll
      for (int e = 0; e < 8; ++e) at[(part * 8 + e) * 40 + ch] = pc[e];
    }
  }

  const f32x4 vz = {0.f, 0.f, 0.f, 0.f};
  f32x4 acc[4] = {vz, vz, vz, vz};
  const int bsw = (lq ^ ((l15 >> 1) & 3)) << 3;
#pragma unroll
  for (int tau = 0; tau < 2; ++tau) {
    const int g = gtab[wid * 2 + tau];
    const u16* at = ATa[wid][tau];
    for (int k = 0; k < 12; ++k) {
      const short8v af = *(const short8v*)(at + (l15 + k + 6) * 40 + lq * 8);
#pragma unroll
      for (int nf = 0; nf < 4; ++nf) {
        const short8v bf = *(const short8v*)(wB + (long)(g * 12 + k) * 2048 + (nf * 16 + l15) * 32 + bsw);
        acc[nf] = __builtin_amdgcn_mfma_f32_16x16x32_bf16(af, bf, acc[nf], 0, 0, 0);
      }
    }
  }
  float* ap = apL[wid];
#pragma unroll
  for (int nf = 0; nf < 4; ++nf)
#pragma unroll
    for (int e = 0; e < 4; ++e)
      ap[(lq * 4 + e) * 68 + nf * 16 + l15] = acc[nf][e];
  __syncthreads();
  // reduce 4 wave-partials into apL[0]
  for (int idx = tid; idx < 1024; idx += 256) {
    const int m = idx >> 6, j = idx & 63;
    apL[0][m * 68 + j] = apL[0][m * 68 + j] + apL[1][m * 68 + j]
                       + apL[2][m * 68 + j] + apL[3][m * 68 + j];
  }
  __syncthreads();
  for (int task = tid; task < 384; task += 256) {
    const int o = task & 31, tt = task >> 5;   // tt 0..11
    float s = skb[o];
#pragma unroll
    for (int c2 = 0; c2 < 32; ++c2)
      s += skw[o * 32 + c2] * (apL[0][tt * 68 + c2] + c1b[c2])
                            * (apL[0][tt * 68 + 32 + c2] + c2b[c2]);
    out[OFF_SAUX + ((long)(b * 32 + o) * 256 + n) * 12 + tt] = s;
  }
}

// ---------------------------------------------------------------- launcher
extern "C" void kernel_launch(void* const* d_in, const int* in_sizes, int n_in,
                              void* d_out, int out_size, void* d_ws, size_t ws_size,
                              hipStream_t stream) {
  const float* x   = (const float*)d_in[0];
  const float* emb = (const float*)d_in[1];
  const float* c1w = (const float*)d_in[2];
  const float* c1b = (const float*)d_in[3];
  const float* c2w = (const float*)d_in[4];
  const float* c2b = (const float*)d_in[5];
  const float* skw = (const float*)d_in[6];
  const float* skb = (const float*)d_in[7];
  const float* rsw = (const float*)d_in[8];
  const float* rsb = (const float*)d_in[9];
  float* out = (float*)d_out;

  u16* xcat = (u16*)d_ws;                                   // 4*416*256*304 elems
  u16* wB   = xcat + (4L * 416 * 256 * 304 + 2048);         // 156*2048
  u16* adjb = wB + 156L * 2048;                             // 256*256

  k_front<<<dim3(9696), dim3(256), 0, stream>>>(x, emb, c1w, c2w, xcat, adjb, wB);
  k_mid<<<dim3(7168), dim3(256), 0, stream>>>(xcat, adjb,
      (const float*)d_in[10], (const float*)d_in[11],
      (const float*)d_in[12], (const float*)d_in[13],
      (const float*)d_in[14], (const float*)d_in[15]);
  k_re4<<<dim3(1536), dim3(256), 0, stream>>>(xcat, (const float*)d_in[16], (const float*)d_in[17]);
  k_convG<<<dim3(3, 256), dim3(256), 0, stream>>>(xcat, wB, c1b, c2b, rsw, rsb, skw, skb, out);
  k_convA<<<dim3(1024), dim3(256), 0, stream>>>(xcat, wB, c1b, c2b, skw, skb, out);
}

// Round 11
// 604.365 us; speedup vs baseline: 1.5967x; 1.5558x over previous
//
#include <hip/hip_runtime.h>

typedef unsigned short u16;
typedef __attribute__((ext_vector_type(8))) short short8v;
typedef __attribute__((ext_vector_type(4))) float f32x4;

#define PSTR 304L              // padded time stride
#define OFF_SAUX 9109504L
#define OFF_S    9502720L
#define CHSTR (32L*256L*PSTR)  // A elems per channel-group g

static __device__ __forceinline__ float bf2f(u16 u) {
  return __uint_as_float(((unsigned int)u) << 16);
}
static __device__ __forceinline__ u16 f2bf(float f) {
  unsigned int i = __float_as_uint(f);
  i += 0x7FFFu + ((i >> 16) & 1u);          // RNE
  return (u16)(i >> 16);
}

static __device__ __forceinline__ void gload16(const void* g, void* l) {
  __builtin_amdgcn_global_load_lds(
      (const __attribute__((address_space(1))) unsigned int*)g,
      (__attribute__((address_space(3))) unsigned int*)l, 16, 0, 0);
}

// ---------------------------------------------------------------- adj softmax
static __device__ void adj_body(int row, const float* __restrict__ emb,
                                u16* __restrict__ adjb) {
  const int m = threadIdx.x;
  __shared__ float sred[8];
  float er[16];
#pragma unroll
  for (int e = 0; e < 16; ++e) er[e] = emb[row * 16 + e];
  float d = 0.f;
#pragma unroll
  for (int e = 0; e < 16; ++e) d += er[e] * emb[m * 16 + e];
  if (m == row) d -= 10.f;
  float v = d;
#pragma unroll
  for (int off = 32; off; off >>= 1) v = fmaxf(v, __shfl_xor(v, off, 64));
  const int wid = m >> 6, lane = m & 63;
  if (lane == 0) sred[wid] = v;
  __syncthreads();
  const float mx = fmaxf(fmaxf(sred[0], sred[1]), fmaxf(sred[2], sred[3]));
  const float p = expf(d - mx);
  v = p;
#pragma unroll
  for (int off = 32; off; off >>= 1) v += __shfl_xor(v, off, 64);
  if (lane == 0) sred[4 + wid] = v;
  __syncthreads();
  const float sum = sred[4] + sred[5] + sred[6] + sred[7];
  adjb[row * 256 + m] = f2bf(p / sum);
}

// ------------------------------------------------- pack conv weights -> bf16
static __device__ void prepw_body(int bid, const float* __restrict__ c1w,
                                  const float* __restrict__ c2w,
                                  u16* __restrict__ wB) {
  const int idx = bid * 256 + threadIdx.x;   // < 156*2048 exactly
  const int kk = idx >> 11;            // g*12+k
  const int rem = idx & 2047;
  const int j = rem >> 5, chp = rem & 31;
  const int pslot = chp >> 3, chlo = chp & 7;
  const int sl = pslot ^ ((j >> 1) & 3);   // logical slot stored here
  const int ch = sl * 8 + chlo;
  const int g = kk / 12, k = kk - g * 12;
  const int cin = g * 32 + ch;
  const float* src = (j < 32) ? c1w : c2w;
  const int jj = j & 31;
  wB[idx] = f2bf(src[(jj * 416 + cin) * 12 + k]);
}

// ------------------------------------------------------- fused norm pipeline
static __device__ __forceinline__ void wscan2(float& s1, float& s2, int lane) {
#pragma unroll
  for (int off = 1; off < 64; off <<= 1) {
    float a = __shfl_up(s1, off, 64);
    float b = __shfl_up(s2, off, 64);
    if (lane >= off) { s1 += a; s2 += b; }
  }
}

static __device__ void norm_body(int bid, const float* __restrict__ x,
                                 u16* __restrict__ xcat) {
  const int wid = threadIdx.x >> 6, lane = threadIdx.x & 63;
  const long row = (long)bid * 4 + wid;
  const int b = (int)(row >> 13);
  const int c = (int)((row >> 8) & 31);
  const int n = (int)(row & 255);
  const float* xr = x + row * 288;
  __shared__ float bufA[4][304], bufB[4][304], cs1[4][312], cs2[4][312], sst[4][80];
  float* bA = bufA[wid];
  float* bB = bufB[wid];
  float* p1 = cs1[wid];
  float* p2 = cs2[wid];
  float* psm = sst[wid];
  float* psi = sst[wid] + 24;
  float* psd = sst[wid] + 48;
  const long chb = (long)b * 416 * 256 + n;

  for (int j = 0; j < 5; ++j) { int t = j * 64 + lane; if (t < 288) bA[t] = xr[t]; }

  auto scanbuf = [&](float* src) {
    float ca = 0.f, cb = 0.f;
    if (lane == 0) { p1[0] = 0.f; p2[0] = 0.f; }
    for (int j = 0; j < 5; ++j) {
      int t = j * 64 + lane;
      float v = (t < 288) ? src[t] : 0.f;
      float s1 = v, s2 = v * v;
      wscan2(s1, s2, lane);
      if (t < 288) { p1[t + 1] = ca + s1; p2[t + 1] = cb + s2; }
      ca += __shfl(s1, 63, 64);
      cb += __shfl(s2, 63, 64);
    }
  };

  // ---- long term_norm, L=48
  scanbuf(bA);
  for (int j = 0; j < 5; ++j) {
    int t = j * 64 + lane; if (t >= 288) continue;
    float S, Q;
    if (t >= 47) { S = p1[t + 1] - p1[t - 47]; Q = p2[t + 1] - p2[t - 47]; }
    else         { S = p1[48];                 Q = p2[48]; }
    float m = S * (1.f / 48.f);
    float var = Q * (1.f / 48.f) - m * m + 1e-5f;
    float sd = sqrtf(var);
    float iv = rsqrtf(var + 1.f);
    float xv = bA[t];
    float x1 = (xv - m) * iv;
    bB[t] = x1;
    xcat[(chb + (long)(c)      * 256) * PSTR + 1 + t] = f2bf(xv);
    xcat[(chb + (long)(32 + c) * 256) * PSTR + 1 + t] = f2bf(x1);
    xcat[(chb + (long)(64 + c) * 256) * PSTR + 1 + t] = f2bf(m);
    xcat[(chb + (long)(96 + c) * 256) * PSTR + 1 + t] = f2bf(sd);
  }
  {
    float S = p1[288] - p1[240], Q = p2[288] - p2[240];
    float m = S * (1.f / 48.f);
    float var = Q * (1.f / 48.f) - m * m + 1e-5f;
    float sd = sqrtf(var);
    if (lane < 12) {
      xcat[(chb + (long)(c)      * 256) * PSTR + 289 + lane] = f2bf(bA[287]);
      xcat[(chb + (long)(64 + c) * 256) * PSTR + 289 + lane] = f2bf(m);
      xcat[(chb + (long)(96 + c) * 256) * PSTR + 289 + lane] = f2bf(sd);
    }
    if (lane == 0) {
      xcat[(chb + (long)(c)      * 256) * PSTR] = 0;
      xcat[(chb + (long)(32 + c) * 256) * PSTR] = 0;
      xcat[(chb + (long)(64 + c) * 256) * PSTR] = 0;
      xcat[(chb + (long)(96 + c) * 256) * PSTR] = 0;
    }
  }
  // ---- seasonal_norm, P=24 (on bB = x1)
  if (lane < 24) {
    float S = 0.f, Q = 0.f;
#pragma unroll
    for (int i2 = 0; i2 < 12; ++i2) { float v = bB[lane + 24 * i2]; S += v; Q += v * v; }
    float m = S * (1.f / 12.f);
    float var = Q * (1.f / 12.f) - m * m + 1e-5f;
    psm[lane] = m; psi[lane] = rsqrtf(var + 1.f); psd[lane] = sqrtf(var);
  }
  for (int j = 0; j < 5; ++j) {
    int t = j * 64 + lane; if (t >= 288) continue;
    int ph = t % 24;
    float m = psm[ph];
    float x2v = (bB[t] - m) * psi[ph];
    bA[t] = x2v;
    xcat[(chb + (long)(128 + c) * 256) * PSTR + 1 + t] = f2bf(x2v);
    xcat[(chb + (long)(160 + c) * 256) * PSTR + 1 + t] = f2bf(m);
    xcat[(chb + (long)(192 + c) * 256) * PSTR + 1 + t] = f2bf(psd[ph]);
  }
  if (lane < 12) {
    xcat[(chb + (long)(160 + c) * 256) * PSTR + 289 + lane] = f2bf(psm[lane]);
    xcat[(chb + (long)(192 + c) * 256) * PSTR + 289 + lane] = f2bf(psd[lane]);
  }
  if (lane == 0) {
    xcat[(chb + (long)(128 + c) * 256) * PSTR] = 0;
    xcat[(chb + (long)(160 + c) * 256) * PSTR] = 0;
    xcat[(chb + (long)(192 + c) * 256) * PSTR] = 0;
  }
  // ---- short term_norm, L=12 (on bA = x2)
  scanbuf(bA);
  for (int j = 0; j < 5; ++j) {
    int t = j * 64 + lane; if (t >= 288) continue;
    float S, Q;
    if (t >= 11) { S = p1[t + 1] - p1[t - 11]; Q = p2[t + 1] - p2[t - 11]; }
    else         { S = p1[12];                 Q = p2[12]; }
    float m = S * (1.f / 12.f);
    float var = Q * (1.f / 12.f) - m * m + 1e-5f;
    float sd = sqrtf(var);
    float iv = rsqrtf(var + 1.f);
    float x3v = (bA[t] - m) * iv;
    xcat[(chb + (long)(224 + c) * 256) * PSTR + 1 + t] = f2bf(x3v);
    xcat[(chb + (long)(256 + c) * 256) * PSTR + 1 + t] = f2bf(m);
    xcat[(chb + (long)(288 + c) * 256) * PSTR + 1 + t] = f2bf(sd);
  }
  {
    float S = p1[288] - p1[276], Q = p2[288] - p2[276];
    float m = S * (1.f / 12.f);
    float var = Q * (1.f / 12.f) - m * m + 1e-5f;
    float sd = sqrtf(var);
    if (lane < 12) {
      xcat[(chb + (long)(256 + c) * 256) * PSTR + 289 + lane] = f2bf(m);
      xcat[(chb + (long)(288 + c) * 256) * PSTR + 289 + lane] = f2bf(sd);
    }
    if (lane == 0) {
      xcat[(chb + (long)(224 + c) * 256) * PSTR] = 0;
      xcat[(chb + (long)(256 + c) * 256) * PSTR] = 0;
      xcat[(chb + (long)(288 + c) * 256) * PSTR] = 0;
    }
  }
}

// ---------------- front: norm (0..8191) | adj (8192..8447) | prepw (8448..9695)
__global__ __launch_bounds__(256) void k_front(const float* __restrict__ x,
    const float* __restrict__ emb, const float* __restrict__ c1w,
    const float* __restrict__ c2w, u16* __restrict__ xcat,
    u16* __restrict__ adjb, u16* __restrict__ wB) {
  const int bid = blockIdx.x;
  if (bid < 8192)       norm_body(bid, x, xcat);
  else if (bid < 8448)  adj_body(bid - 8192, emb, adjb);
  else                  prepw_body(bid - 8448, c1w, c2w, wB);
}

// --------------------------------------------- residual extrapolation (tiny)
static __device__ void re_body(long gid, u16* __restrict__ xcat,
                               const float* __restrict__ W,
                               const float* __restrict__ bias, int srcch) {
  const int o = (int)(gid % 384);
  const long bn = gid / 384;
  const int n = (int)(bn & 255);
  const int b = (int)(bn >> 8);
  const float* wr = W + o * 160;
  float acc = bias[o];
  for (int c = 0; c < 32; ++c) {
    const long rb = ((long)(b * 416 + srcch + c) * 256 + n) * PSTR + 284;
#pragma unroll
    for (int k = 0; k < 5; ++k) acc += wr[c * 5 + k] * bf2f(xcat[rb + k]);
  }
  const int cd = o & 31, p = o >> 5;
  xcat[((long)(b * 416 + srcch + cd) * 256 + n) * PSTR + 289 + p] = f2bf(acc);
}

__global__ __launch_bounds__(256) void k_re4(u16* __restrict__ xcat,
                                             const float* __restrict__ W,
                                             const float* __restrict__ bias) {
  re_body((long)blockIdx.x * 256 + threadIdx.x, xcat, W, bias, 320);
}

// ----------------------------------------------------- spatial norm (MFMA)
static __device__ void spatial_body(int sid, u16* __restrict__ xcat,
                                    const u16* __restrict__ adjb) {
  const int gx = sid % 20;       // 0..19
  const int slice = sid / 20;    // 0..127
  const int tcn = gx >> 2, ncb = gx & 3;
  const int b = slice >> 5, c = slice & 31;
  const int t0 = tcn * 64, n0 = ncb * 64;
  const int tid = threadIdx.x;
  const int wid = tid >> 6, lane = tid & 63;
  const int wm = wid >> 1, wn = wid & 1;
  const int l15 = lane & 15, lq = lane >> 4;
  __shared__ __align__(16) u16 BT[2][64 * 40];
  __shared__ __align__(16) u16 BT2[2][64 * 40];
  const f32x4 vz = {0.f, 0.f, 0.f, 0.f};
  f32x4 aM[2][2], aV[2][2];
#pragma unroll
  for (int i = 0; i < 2; ++i)
#pragma unroll
    for (int j = 0; j < 2; ++j) { aM[i][j] = vz; aV[i][j] = vz; }
  const long base7 = (long)(b * 416 + 224 + c) * 256;
  u16 rv[8];
#pragma unroll
  for (int r = 0; r < 8; ++r) {
    int idx = tid + r * 256; int ml = idx >> 6, s = idx & 63;
    rv[r] = xcat[(base7 + ml) * PSTR + 1 + t0 + s];
  }
#pragma unroll
  for (int r = 0; r < 8; ++r) {
    int idx = tid + r * 256; int ml = idx >> 6, s = idx & 63;
    float v = bf2f(rv[r]);
    BT[0][s * 40 + ml] = rv[r];
    BT2[0][s * 40 + ml] = f2bf(v * v);
  }
  __syncthreads();
  int cur = 0;
  for (int kk = 0; kk < 8; ++kk) {
    u16 rn[8];
    if (kk < 7) {
#pragma unroll
      for (int r = 0; r < 8; ++r) {
        int idx = tid + r * 256; int ml = idx >> 6, s = idx & 63;
        rn[r] = xcat[(base7 + (long)((kk + 1) * 32 + ml)) * PSTR + 1 + t0 + s];
      }
    }
    const short8v a0 = *(const short8v*)(adjb + (long)(n0 + wm * 32 + l15) * 256 + kk * 32 + lq * 8);
    const short8v a1 = *(const short8v*)(adjb + (long)(n0 + wm * 32 + 16 + l15) * 256 + kk * 32 + lq * 8);
    const u16* bt = BT[cur];
    const u16* bq = BT2[cur];
    const short8v b0 = *(const short8v*)(bt + (wn * 32 + l15) * 40 + lq * 8);
    const short8v b1 = *(const short8v*)(bt + (wn * 32 + 16 + l15) * 40 + lq * 8);
    const short8v q0 = *(const short8v*)(bq + (wn * 32 + l15) * 40 + lq * 8);
    const short8v q1 = *(const short8v*)(bq + (wn * 32 + 16 + l15) * 40 + lq * 8);
    aM[0][0] = __builtin_amdgcn_mfma_f32_16x16x32_bf16(a0, b0, aM[0][0], 0, 0, 0);
    aM[0][1] = __builtin_amdgcn_mfma_f32_16x16x32_bf16(a0, b1, aM[0][1], 0, 0, 0);
    aM[1][0] = __builtin_amdgcn_mfma_f32_16x16x32_bf16(a1, b0, aM[1][0], 0, 0, 0);
    aM[1][1] = __builtin_amdgcn_mfma_f32_16x16x32_bf16(a1, b1, aM[1][1], 0, 0, 0);
    aV[0][0] = __builtin_amdgcn_mfma_f32_16x16x32_bf16(a0, q0, aV[0][0], 0, 0, 0);
    aV[0][1] = __builtin_amdgcn_mfma_f32_16x16x32_bf16(a0, q1, aV[0][1], 0, 0, 0);
    aV[1][0] = __builtin_amdgcn_mfma_f32_16x16x32_bf16(a1, q0, aV[1][0], 0, 0, 0);
    aV[1][1] = __builtin_amdgcn_mfma_f32_16x16x32_bf16(a1, q1, aV[1][1], 0, 0, 0);
    __syncthreads();
    if (kk < 7) {
#pragma unroll
      for (int r = 0; r < 8; ++r) {
        int idx = tid + r * 256; int ml = idx >> 6, s = idx & 63;
        float v = bf2f(rn[r]);
        BT[cur ^ 1][s * 40 + ml] = rn[r];
        BT2[cur ^ 1][s * 40 + ml] = f2bf(v * v);
      }
    }
    __syncthreads();
    cur ^= 1;
  }
#pragma unroll
  for (int mf = 0; mf < 2; ++mf)
#pragma unroll
    for (int nf = 0; nf < 2; ++nf)
#pragma unroll
      for (int e = 0; e < 4; ++e) {
        const int i = wm * 32 + mf * 16 + lq * 4 + e;
        const int j = wn * 32 + nf * 16 + l15;
        const int nn = n0 + i, tt2 = t0 + j;
        if (tt2 < 288) {
          const float mean = aM[mf][nf][e], ex2 = aV[mf][nf][e];
          const float var = ex2 - mean * mean + 1e-5f;
          const float sd = sqrtf(var);
          const float iv = rsqrtf(var + 1.f);
          const float x3c = bf2f(xcat[(base7 + nn) * PSTR + 1 + tt2]);
          const float x4 = (x3c - mean) * iv;
          const long r10 = ((long)(b * 416 + 320 + c) * 256 + nn) * PSTR;
          const long r11 = ((long)(b * 416 + 352 + c) * 256 + nn) * PSTR;
          const long r12 = ((long)(b * 416 + 384 + c) * 256 + nn) * PSTR;
          xcat[r10 + 1 + tt2] = f2bf(x4);
          xcat[r11 + 1 + tt2] = f2bf(mean);
          xcat[r12 + 1 + tt2] = f2bf(sd);
          if (tt2 == 287) {
            for (int p = 0; p < 12; ++p) {
              xcat[r11 + 289 + p] = f2bf(mean);
              xcat[r12 + 289 + p] = f2bf(sd);
            }
          }
          if (tt2 == 0) { xcat[r10] = 0; xcat[r11] = 0; xcat[r12] = 0; }
        }
      }
}

// ---------------- mid: spatial (0..2559) | re1/re2/re3 (2560..7167)
__global__ __launch_bounds__(256) void k_mid(u16* __restrict__ xcat,
    const u16* __restrict__ adjb,
    const float* __restrict__ w1, const float* __restrict__ b1,
    const float* __restrict__ w2, const float* __restrict__ b2,
    const float* __restrict__ w3, const float* __restrict__ b3) {
  const int bid = blockIdx.x;
  if (bid < 2560) { spatial_body(bid, xcat, adjb); return; }
  const int sub = bid - 2560;             // 0..4607
  const int which = sub / 1536;
  const long gid = (long)(sub - which * 1536) * 256 + threadIdx.x;
  if (which == 0)      re_body(gid, xcat, w1, b1, 32);
  else if (which == 1) re_body(gid, xcat, w2, b2, 128);
  else                 re_body(gid, xcat, w3, b3, 224);
}

// --------------------------------------------------- main time-conv (g1,g2)
// M=128 t-tile (MT=2) for t0=0,128; 64-wide tail (MT=1) at t0=256.
// Per wave: n own, A LDS swizzled; B gload_lds 8KB pairs, 2-buffer.
template<int MT>
static __device__ void convG_body(int t0, int by,
    const u16* __restrict__ xcat, const u16* __restrict__ wB,
    const float* __restrict__ c1b, const float* __restrict__ c2b,
    const float* __restrict__ rsw, const float* __restrict__ rsb,
    const float* __restrict__ skw, const float* __restrict__ skb,
    float* __restrict__ out, unsigned char* smem) {
  const int b = by >> 6;
  const int tid = threadIdx.x;
  const int wid = tid >> 6, lane = tid & 63;
  const int n_abs = (by & 63) * 4 + wid;
  const int l15 = lane & 15, lq = lane >> 4;
  constexpr int NCH = (MT == 2) ? 9 : 5;     // staging chunks per lane
  constexpr int TKS = (MT == 2) ? 18 : 10;   // 8-t chunks per channel

  u16* Asm = (u16*)smem;                 // 4 waves x 5760 u16 = 46080 B
  u16* Bsm = (u16*)(smem + 46080);       // 2 bufs x 2 blocks x 2048 u16

  int sch[NCH], stk[NCH];
  const u16* baseR[NCH];
#pragma unroll
  for (int r = 0; r < NCH; ++r) {
    int cc = r * 64 + lane;
    int s = cc / TKS, tk = cc - s * TKS;
    sch[r] = s; stk[r] = tk;
    baseR[r] = xcat + ((long)(b * 416 + s) * 256 + n_abs) * PSTR + t0 + tk * 8;
  }
  u16* aw = Asm + wid * 5760;

#define AWRITE() { \
    _Pragma("unroll") \
    for (int r = 0; r < NCH; ++r) { \
      u16 pc[8]; *(uint4*)pc = aR[r]; \
      const int pcol = ((((sch[r] >> 3) ^ stk[r]) & 3) << 3) + (sch[r] & 7); \
      _Pragma("unroll") \
      for (int e = 0; e < 8; ++e) aw[(stk[r] * 8 + e) * 40 + pcol] = pc[e]; \
    } }

  // ---- prologue: A(g=0) into LDS, aR <- g=1, stage B pair 0
  uint4 aR[NCH];
#pragma unroll
  for (int r = 0; r < NCH; ++r) aR[r] = *(const uint4*)baseR[r];
  AWRITE();
#pragma unroll
  for (int r = 0; r < NCH; ++r) aR[r] = *(const uint4*)(baseR[r] + CHSTR);
  gload16(wB + 0 * 2048 + wid * 512 + lane * 8, Bsm + 0 + wid * 512);
  gload16(wB + 1 * 2048 + wid * 512 + lane * 8, Bsm + 2048 + wid * 512);
  __syncthreads();   // drains DMA: pair 0 ready; A(g0) written

  const f32x4 vz = {0.f, 0.f, 0.f, 0.f};
  f32x4 acc[4 * MT][4];
#pragma unroll
  for (int i = 0; i < 4 * MT; ++i)
#pragma unroll
    for (int j = 0; j < 4; ++j) acc[i][j] = vz;

  const u16* bwl = Bsm + l15 * 32 + ((lq ^ ((l15 >> 1) & 3)) << 3);

  int p = 0;  // pair index 0..77; pair p = blocks 2p, 2p+1
  for (int g = 0; g < 13; ++g) {
    for (int kp = 0; kp < 6; ++kp) {
      if (p < 77) {  // stage next pair into the other buffer
        const long kkn = (long)(p + 1) * 2;
        const int bufn = ((p + 1) & 1) * 4096;
        gload16(wB + kkn * 2048 + wid * 512 + lane * 8, Bsm + bufn + wid * 512);
        gload16(wB + (kkn + 1) * 2048 + wid * 512 + lane * 8, Bsm + bufn + 2048 + wid * 512);
      }
      const int bufc = (p & 1) * 4096;
#pragma unroll
      for (int kh = 0; kh < 2; ++kh) {
        const int K = kp * 2 + kh;
        short8v af[4 * MT], bf[4];
#pragma unroll
        for (int f = 0; f < 4 * MT; ++f) {
          const int tt = K + f * 16 + l15;
          af[f] = *(const short8v*)(aw + tt * 40 + (((lq ^ (tt >> 3)) & 3) << 3));
        }
#pragma unroll
        for (int f = 0; f < 4; ++f)
          bf[f] = *(const short8v*)(bwl + bufc + kh * 2048 + f * 512);
#pragma unroll
        for (int i = 0; i < 4 * MT; ++i)
#pragma unroll
          for (int j = 0; j < 4; ++j)
            acc[i][j] = __builtin_amdgcn_mfma_f32_16x16x32_bf16(af[i], bf[j], acc[i][j], 0, 0, 0);
      }
      __syncthreads();  // drains DMA(p+1); all waves done reading buf p
      ++p;
    }
    if (g < 12) {  // A rewrite for g+1 (per-wave private, program order)
      AWRITE();
      if (g < 11) {
#pragma unroll
        for (int r = 0; r < NCH; ++r) aR[r] = *(const uint4*)(baseR[r] + (long)(g + 2) * CHSTR);
      }
    }
  }
#undef AWRITE
  __syncthreads();

  // ---- epilogue: MT passes of 64 rows; per-wave pad-33 LDS, fused 1x1
#pragma unroll
  for (int pass = 0; pass < MT; ++pass) {
    float* pw = (float*)smem + wid * 2112;   // 64 rows x 33 f32 per wave
#pragma unroll
    for (int fi = 0; fi < 4; ++fi)
#pragma unroll
      for (int nf = 0; nf < 2; ++nf)
#pragma unroll
        for (int e = 0; e < 4; ++e) {
          const int trow = fi * 16 + lq * 4 + e;
          const int cch = nf * 16 + l15;
          const float g1 = acc[pass * 4 + fi][nf][e] + c1b[cch];
          const float g2 = acc[pass * 4 + fi][nf + 2][e] + c2b[cch];
          pw[trow * 33 + cch] = g1 * g2;
        }
    float pv[32];
    {
      const float* prow = pw + lane * 33;
#pragma unroll
      for (int c = 0; c < 32; ++c) pv[c] = prow[c];
    }
    const int t = t0 + pass * 64 + lane;
    if (t0 + pass * 64 + 63 < 278) {  // uniform residual-only path
      for (int o = 0; o < 32; ++o) {
        float s = rsb[o];
        const float* wr = rsw + o * 32;
#pragma unroll
        for (int c = 0; c < 32; ++c) s += wr[c] * pv[c];
        out[((long)(b * 32 + o) * 256 + n_abs) * 278 + t] = s;
      }
    } else {              // mixed res / skip / discard
      const bool isres = t < 278;
      const bool isskip = (t >= 278) && (t < 290);
      for (int o = 0; o < 32; ++o) {
        const float* wr = (isres ? rsw : skw) + o * 32;
        float s = (isres ? rsb : skb)[o];
#pragma unroll
        for (int c = 0; c < 32; ++c) s += wr[c] * pv[c];
        if (isres)       out[((long)(b * 32 + o) * 256 + n_abs) * 278 + t] = s;
        else if (isskip) out[OFF_S + ((long)(b * 32 + o) * 256 + n_abs) * 12 + (t - 278)] = s;
      }
    }
  }
}

// Grid (3,256): x=0,1 -> 128-wide tiles; x=2 -> 64-wide tail at t0=256.
__global__ __launch_bounds__(256, 2) void k_convG(
    const u16* __restrict__ xcat, const u16* __restrict__ wB,
    const float* __restrict__ c1b, const float* __restrict__ c2b,
    const float* __restrict__ rsw, const float* __restrict__ rsb,
    const float* __restrict__ skw, const float* __restrict__ skb,
    float* __restrict__ out) {
  __shared__ __align__(16) unsigned char smem[62464];
  if (blockIdx.x < 2)
    convG_body<2>(blockIdx.x * 128, blockIdx.y, xcat, wB, c1b, c2b, rsw, rsb, skw, skb, out, smem);
  else
    convG_body<1>(256, blockIdx.y, xcat, wB, c1b, c2b, rsw, rsb, skw, skb, out, smem);
}

// ------------------------------------------- aux conv (a1,a2) tail -> s_aux
// Grid 1024: block = one (b,n); 4 waves split the 8 g-groups 2-each; LDS
// partial sums reduced across waves; vectorized uint4 staging from t=272.
__global__ __launch_bounds__(256) void k_convA(const u16* __restrict__ xcat,
    const u16* __restrict__ wB, const float* __restrict__ c1b,
    const float* __restrict__ c2b, const float* __restrict__ skw,
    const float* __restrict__ skb, float* __restrict__ out) {
  const int tid = threadIdx.x;
  const int wid = tid >> 6, lane = tid & 63;
  const int row = blockIdx.x;            // (b,n)
  const int b = row >> 8, n = row & 255;
  const int l15 = lane & 15, lq = lane >> 4;
  __shared__ __align__(16) u16 ATa[4][2][36 * 40];  // per wave, 2 g-tiles
  __shared__ float apL[4][16 * 68];
  const int gtab[8] = {2, 3, 5, 6, 8, 9, 11, 12};
  const long bnbase = (long)b * 416 * 256 + n;

  // stage: per wave, its 2 g-tiles; tile rows t' = t-272 in [0,32)
#pragma unroll
  for (int tau = 0; tau < 2; ++tau) {
    const int g = gtab[wid * 2 + tau];
    u16* at = ATa[wid][tau];
#pragma unroll
    for (int h = 0; h < 2; ++h) {
      const int c = lane + h * 64;       // 0..127
      const int ch = c >> 2, part = c & 3;
      const uint4 v = *(const uint4*)(xcat +
          (bnbase + (long)(g * 32 + ch) * 256) * PSTR + 272 + part * 8);
      u16 pc[8]; *(uint4*)pc = v;
#pragma unroll
      for (int e = 0; e < 8; ++e) at[(part * 8 + e) * 40 + ch] = pc[e];
    }
  }

  const f32x4 vz = {0.f, 0.f, 0.f, 0.f};
  f32x4 acc[4] = {vz, vz, vz, vz};
  const int bsw = (lq ^ ((l15 >> 1) & 3)) << 3;
#pragma unroll
  for (int tau = 0; tau < 2; ++tau) {
    const int g = gtab[wid * 2 + tau];
    const u16* at = ATa[wid][tau];
    for (int k = 0; k < 12; ++k) {
      const short8v af = *(const short8v*)(at + (l15 + k + 6) * 40 + lq * 8);
#pragma unroll
      for (int nf = 0; nf < 4; ++nf) {
        const short8v bf = *(const short8v*)(wB + (long)(g * 12 + k) * 2048 + (nf * 16 + l15) * 32 + bsw);
        acc[nf] = __builtin_amdgcn_mfma_f32_16x16x32_bf16(af, bf, acc[nf], 0, 0, 0);
      }
    }
  }
  float* ap = apL[wid];
#pragma unroll
  for (int nf = 0; nf < 4; ++nf)
#pragma unroll
    for (int e = 0; e < 4; ++e)
      ap[(lq * 4 + e) * 68 + nf * 16 + l15] = acc[nf][e];
  __syncthreads();
  // reduce 4 wave-partials into apL[0]
  for (int idx = tid; idx < 1024; idx += 256) {
    const int m = idx >> 6, j = idx & 63;
    apL[0][m * 68 + j] = apL[0][m * 68 + j] + apL[1][m * 68 + j]
                       + apL[2][m * 68 + j] + apL[3][m * 68 + j];
  }
  __syncthreads();
  for (int task = tid; task < 384; task += 256) {
    const int o = task & 31, tt = task >> 5;   // tt 0..11
    float s = skb[o];
#pragma unroll
    for (int c2 = 0; c2 < 32; ++c2)
      s += skw[o * 32 + c2] * (apL[0][tt * 68 + c2] + c1b[c2])
                            * (apL[0][tt * 68 + 32 + c2] + c2b[c2]);
    out[OFF_SAUX + ((long)(b * 32 + o) * 256 + n) * 12 + tt] = s;
  }
}

// ---------------------------------------------------------------- launcher
extern "C" void kernel_launch(void* const* d_in, const int* in_sizes, int n_in,
                              void* d_out, int out_size, void* d_ws, size_t ws_size,
                              hipStream_t stream) {
  const float* x   = (const float*)d_in[0];
  const float* emb = (const float*)d_in[1];
  const float* c1w = (const float*)d_in[2];
  const float* c1b = (const float*)d_in[3];
  const float* c2w = (const float*)d_in[4];
  const float* c2b = (const float*)d_in[5];
  const float* skw = (const float*)d_in[6];
  const float* skb = (const float*)d_in[7];
  const float* rsw = (const float*)d_in[8];
  const float* rsb = (const float*)d_in[9];
  float* out = (float*)d_out;

  u16* xcat = (u16*)d_ws;                                   // 4*416*256*304 elems
  u16* wB   = xcat + (4L * 416 * 256 * 304 + 2048);         // 156*2048
  u16* adjb = wB + 156L * 2048;                             // 256*256

  k_front<<<dim3(9696), dim3(256), 0, stream>>>(x, emb, c1w, c2w, xcat, adjb, wB);
  k_mid<<<dim3(7168), dim3(256), 0, stream>>>(xcat, adjb,
      (const float*)d_in[10], (const float*)d_in[11],
      (const float*)d_in[12], (const float*)d_in[13],
      (const float*)d_in[14], (const float*)d_in[15]);
  k_re4<<<dim3(1536), dim3(256), 0, stream>>>(xcat, (const float*)d_in[16], (const float*)d_in[17]);
  k_convG<<<dim3(3, 256), dim3(256), 0, stream>>>(xcat, wB, c1b, c2b, rsw, rsb, skw, skb, out);
  k_convA<<<dim3(1024), dim3(256), 0, stream>>>(xcat, wB, c1b, c2b, skw, skb, out);
}